// Round 17
// baseline (443.724 us; speedup 1.0000x reference)
//
#include <hip/hip_runtime.h>

// bf16 handled as raw ushort (bf16 = top 16 bits of fp32).
typedef unsigned short bfu;
typedef unsigned int u32;
typedef __attribute__((ext_vector_type(8))) short bf16x8;   // 8 bf16 = 4 VGPRs
typedef __attribute__((ext_vector_type(4))) float f32x4;

#define SCALE_F 0.17677669529663687f

__device__ __forceinline__ bfu f2b(float f) {
  unsigned int u = __float_as_uint(f);
  u += 0x7fffu + ((u >> 16) & 1u);   // round-to-nearest-even
  return (bfu)(u >> 16);
}
__device__ __forceinline__ unsigned pk2(float a, float b) {
  return ((unsigned)f2b(b) << 16) | (unsigned)f2b(a);
}
__device__ __forceinline__ void gload_lds16(const void* g, void* l) {
  __builtin_amdgcn_global_load_lds(
      (const __attribute__((address_space(1))) u32*)g,
      (__attribute__((address_space(3))) u32*)l, 16, 0, 0);
}

// The r15-verified fragment permutation: dest lane (l15,l4), element e reads
// source lane l15 + 32*(l4&1) (e<4) / +16 (e>=4), register pair s[n = l4>>1],
// packed component (e>>2 selects .x/.y-half, e&3 the bf16 within the pair
// sequence). Converts swapped/normal D-layout acc pairs into MFMA fragments.
__device__ __forceinline__ bf16x8 permfrag(uint2 s0, uint2 s1,
                                           int bpA, int bpB, int nsel) {
  u32 a0x = __builtin_amdgcn_ds_bpermute(bpA, (int)s0.x);
  u32 a0y = __builtin_amdgcn_ds_bpermute(bpA, (int)s0.y);
  u32 a1x = __builtin_amdgcn_ds_bpermute(bpA, (int)s1.x);
  u32 a1y = __builtin_amdgcn_ds_bpermute(bpA, (int)s1.y);
  u32 b0x = __builtin_amdgcn_ds_bpermute(bpB, (int)s0.x);
  u32 b0y = __builtin_amdgcn_ds_bpermute(bpB, (int)s0.y);
  u32 b1x = __builtin_amdgcn_ds_bpermute(bpB, (int)s1.x);
  u32 b1y = __builtin_amdgcn_ds_bpermute(bpB, (int)s1.y);
  union { uint4 u; bf16x8 v; } cv;
  cv.u.x = nsel ? a1x : a0x;
  cv.u.y = nsel ? a1y : a0y;
  cv.u.z = nsel ? b1x : b0x;
  cv.u.w = nsel ? b1y : b0y;
  return cv.v;
}

// Prep: cvt w_qkv [768][256] f32 -> bf16 (N x K), w_out [256][256] likewise,
// and gather the 64x64 relative-position bias table (f32).
__global__ void prep_kernel(const float* __restrict__ wq, const float* __restrict__ wo,
                            const float* __restrict__ pe, const int* __restrict__ rel,
                            bfu* __restrict__ wqB, bfu* __restrict__ woB,
                            float* __restrict__ bias)
{
  int t = blockIdx.x * 256 + threadIdx.x;
  if (t < 196608) wqB[t] = f2b(wq[t]);
  if (t < 65536)  woB[t] = f2b(wo[t]);
  if (t < 4096)   { int r0 = rel[2 * t], r1 = rel[2 * t + 1]; bias[t] = pe[r0 * 15 + r1]; }
}

// Fused qkv-projection + window attention, register-resident K/V/P via
// permfrag (no LDS for q/k/v/p). One block per (bl, win), 256 thr = 4 waves,
// 2 heads per wave sequentially. LDS = xwin 32 KB + 4 x 256 B inv = 33792 B
// -> with __launch_bounds__(256,3) (VGPR <= ~168): 3 blocks/CU = 12 waves.
__global__ __launch_bounds__(256, 3)
void qkv_attn(const float* __restrict__ x, const bfu* __restrict__ wqB,
              const float* __restrict__ b_qkv, const float* __restrict__ bias,
              bfu* __restrict__ aout)
{
  __shared__ __align__(16) char slds[33792];
  const int t = threadIdx.x;
  const int lane = t & 63, wid = t >> 6;       // 4 waves
  const int l15 = lane & 15, l4 = lane >> 4;
  const int blwin = blockIdx.x;
  const int bl = blwin >> 8, win = blwin & 255;

  // ---- stage x window: wave stages 16 tokens (2 y-rows) as bf16, swizzled ----
  #pragma unroll
  for (int i = 0; i < 16; ++i) {
    int tok = (wid << 4) + i;
    int y = ((win >> 4) << 3) | (tok >> 3);
    int xp = ((win & 15) << 3) | (tok & 7);
    const float* px = x + (((size_t)bl * 16384) + (size_t)y * 128 + xp) * 256 + (lane << 2);
    float4 v = *(const float4*)px;
    uint2 d; d.x = pk2(v.x, v.y); d.y = pk2(v.z, v.w);
    *(uint2*)(slds + tok * 512 + (((lane >> 1) ^ (tok & 15)) << 4) + ((lane & 1) << 3)) = d;
  }
  __syncthreads();   // only block-wide barrier

  float* invB = (float*)(slds + 32768 + wid * 256);

  const int bpA = (l15 + ((l4 & 1) << 5)) << 2;
  const int bpB = bpA + 64;
  const int nsel = l4 >> 1;

  #pragma unroll 1
  for (int hh = 0; hh < 2; ++hh) {
    const int h = (wid << 1) | hh;

    // ---- fused Q/K/V mini-GEMMs (r12/r15-verified loop) ----
    const bfu* wQ = wqB + (size_t)(h * 32) * 256;
    const bfu* wK = wqB + (size_t)(256 + h * 32) * 256;
    const bfu* wV = wqB + (size_t)(512 + h * 32) * 256;
    const int woff = l15 * 256 + (l4 << 3);
    f32x4 aQ[2][4] = {}, aK[2][4] = {}, aV[4][2] = {};
    #pragma unroll
    for (int kt = 0; kt < 8; ++kt) {
      bf16x8 xf[4];
      #pragma unroll
      for (int m = 0; m < 4; ++m) {
        int tok = (m << 4) + l15;
        int u = ((kt << 2) + l4) ^ (tok & 15);
        xf[m] = *(const bf16x8*)(slds + tok * 512 + (u << 4));
      }
      bf16x8 q0 = *(const bf16x8*)(wQ + woff + (kt << 5));
      bf16x8 q1 = *(const bf16x8*)(wQ + woff + (kt << 5) + 4096);
      bf16x8 k0 = *(const bf16x8*)(wK + woff + (kt << 5));
      bf16x8 k1 = *(const bf16x8*)(wK + woff + (kt << 5) + 4096);
      bf16x8 v0 = *(const bf16x8*)(wV + woff + (kt << 5));
      bf16x8 v1 = *(const bf16x8*)(wV + woff + (kt << 5) + 4096);
      #pragma unroll
      for (int m = 0; m < 4; ++m) {
        aQ[0][m] = __builtin_amdgcn_mfma_f32_16x16x32_bf16(q0, xf[m], aQ[0][m], 0, 0, 0);
        aQ[1][m] = __builtin_amdgcn_mfma_f32_16x16x32_bf16(q1, xf[m], aQ[1][m], 0, 0, 0);
        aK[0][m] = __builtin_amdgcn_mfma_f32_16x16x32_bf16(k0, xf[m], aK[0][m], 0, 0, 0);
        aK[1][m] = __builtin_amdgcn_mfma_f32_16x16x32_bf16(k1, xf[m], aK[1][m], 0, 0, 0);
        aV[m][0] = __builtin_amdgcn_mfma_f32_16x16x32_bf16(xf[m], v0, aV[m][0], 0, 0, 0);
        aV[m][1] = __builtin_amdgcn_mfma_f32_16x16x32_bf16(xf[m], v1, aV[m][1], 0, 0, 0);
      }
    }

    // ---- pack accs (+bias) to bf16 pairs; frees the 96 f32 acc regs ----
    uint2 aQb[2][4], aKb[2][4], aVb[4][2];
    {
      const float* bQ = b_qkv + h * 32;
      const float* bK = b_qkv + 256 + h * 32;
      const float* bV = b_qkv + 512 + h * 32;
      #pragma unroll
      for (int n = 0; n < 2; ++n) {
        float4 bq = *(const float4*)(bQ + (n << 4) + (l4 << 2));
        float4 bk = *(const float4*)(bK + (n << 4) + (l4 << 2));
        #pragma unroll
        for (int m = 0; m < 4; ++m) {
          aQb[n][m].x = pk2(aQ[n][m][0] + bq.x, aQ[n][m][1] + bq.y);
          aQb[n][m].y = pk2(aQ[n][m][2] + bq.z, aQ[n][m][3] + bq.w);
          aKb[n][m].x = pk2(aK[n][m][0] + bk.x, aK[n][m][1] + bk.y);
          aKb[n][m].y = pk2(aK[n][m][2] + bk.z, aK[n][m][3] + bk.w);
        }
      }
      #pragma unroll
      for (int m = 0; m < 4; ++m)
        #pragma unroll
        for (int n = 0; n < 2; ++n) {
          float bv = bV[(n << 4) + l15];
          aVb[m][n].x = pk2(aV[m][n][0] + bv, aV[m][n][1] + bv);
          aVb[m][n].y = pk2(aV[m][n][2] + bv, aV[m][n][3] + bv);
        }
    }

    // ---- Q/K fragments via permfrag (r15-verified pattern) ----
    bf16x8 qf[4], kf[4];
    #pragma unroll
    for (int i = 0; i < 4; ++i) {
      qf[i] = permfrag(aQb[0][i], aQb[1][i], bpA, bpB, nsel);
      kf[i] = permfrag(aKb[0][i], aKb[1][i], bpA, bpB, nsel);
    }

    // S^T[j][i] = mfma(K, Q): reg r -> j = mj*16 + l4*4 + r; col i = ni*16 + l15.
    f32x4 st[4][4] = {};
    #pragma unroll
    for (int mj = 0; mj < 4; ++mj)
      #pragma unroll
      for (int ni = 0; ni < 4; ++ni)
        st[mj][ni] = __builtin_amdgcn_mfma_f32_16x16x32_bf16(kf[mj], qf[ni], st[mj][ni], 0, 0, 0);

    // scale + bias
    #pragma unroll
    for (int ni = 0; ni < 4; ++ni) {
      int i = (ni << 4) + l15;
      #pragma unroll
      for (int mj = 0; mj < 4; ++mj) {
        float4 bb = *(const float4*)(bias + i * 64 + (mj << 4) + (l4 << 2));
        st[mj][ni][0] = fmaf(st[mj][ni][0], SCALE_F, bb.x);
        st[mj][ni][1] = fmaf(st[mj][ni][1], SCALE_F, bb.y);
        st[mj][ni][2] = fmaf(st[mj][ni][2], SCALE_F, bb.z);
        st[mj][ni][3] = fmaf(st[mj][ni][3], SCALE_F, bb.w);
      }
    }

    // softmax over j per owned q-row; pack unnormalized P to bf16 pairs.
    uint2 stb[4][4];   // [mj][ni], same pack layout as aQb -> permfrag-able
    #pragma unroll
    for (int ni = 0; ni < 4; ++ni) {
      float mx = st[0][ni][0];
      #pragma unroll
      for (int mj = 0; mj < 4; ++mj)
        #pragma unroll
        for (int r = 0; r < 4; ++r)
          mx = fmaxf(mx, st[mj][ni][r]);
      mx = fmaxf(mx, __shfl_xor(mx, 16));
      mx = fmaxf(mx, __shfl_xor(mx, 32));
      float sum = 0.f;
      #pragma unroll
      for (int mj = 0; mj < 4; ++mj)
        #pragma unroll
        for (int r = 0; r < 4; ++r) {
          float p = __expf(st[mj][ni][r] - mx);
          st[mj][ni][r] = p;
          sum += p;
        }
      sum += __shfl_xor(sum, 16);
      sum += __shfl_xor(sum, 32);
      if (l4 == 0) invB[(ni << 4) + l15] = 1.0f / sum;
      #pragma unroll
      for (int mj = 0; mj < 4; ++mj) {
        stb[mj][ni].x = pk2(st[mj][ni][0], st[mj][ni][1]);
        stb[mj][ni].y = pk2(st[mj][ni][2], st[mj][ni][3]);
      }
    }

    // ---- V fragments via permfrag ----
    bf16x8 vf[2][2];
    #pragma unroll
    for (int nj = 0; nj < 2; ++nj)
      #pragma unroll
      for (int ks = 0; ks < 2; ++ks)
        vf[nj][ks] = permfrag(aVb[ks * 2][nj], aVb[ks * 2 + 1][nj], bpA, bpB, nsel);

    // PV: O[i][c] = sum_j P[i][j] * Vt[c][j]; pf via permfrag of stb.
    f32x4 oacc[4][2] = {};
    #pragma unroll
    for (int mi = 0; mi < 4; ++mi) {
      bf16x8 pf0 = permfrag(stb[0][mi], stb[1][mi], bpA, bpB, nsel);
      bf16x8 pf1 = permfrag(stb[2][mi], stb[3][mi], bpA, bpB, nsel);
      #pragma unroll
      for (int nj = 0; nj < 2; ++nj) {
        oacc[mi][nj] = __builtin_amdgcn_mfma_f32_16x16x32_bf16(pf0, vf[nj][0], oacc[mi][nj], 0, 0, 0);
        oacc[mi][nj] = __builtin_amdgcn_mfma_f32_16x16x32_bf16(pf1, vf[nj][1], oacc[mi][nj], 0, 0, 0);
      }
    }

    // epilogue: row i = mi*16 + l4*4 + r, col c = nj*16 + l15
    #pragma unroll
    for (int mi = 0; mi < 4; ++mi) {
      #pragma unroll
      for (int r = 0; r < 4; ++r) {
        int tok = (mi << 4) + (l4 << 2) + r;
        float inv = invB[tok];
        int y = ((win >> 4) << 3) | (tok >> 3);
        int xp = ((win & 15) << 3) | (tok & 7);
        size_t p = ((size_t)bl * 128 + y) * 128 + xp;
        bfu* dst = aout + p * 256 + h * 32;
        #pragma unroll
        for (int nj = 0; nj < 2; ++nj)
          dst[(nj << 4) + l15] = f2b(oacc[mi][nj][r] * inv);
      }
    }
  }
}

// Out-projection GEMM (round-8-verified): C[m][n] = sum_k A[m][k]*B[n][k] + bias[n].
// BK=32, double-buffered, STAGE(next) -> compute -> full barrier. f32 out.
template<int NBN>
__global__ __launch_bounds__(256)
void mfma_gemm(const bfu* __restrict__ A, const bfu* __restrict__ B,
               const float* __restrict__ bias, float* __restrict__ out)
{
  __shared__ __align__(16) char lds[32768];
  const int t = threadIdx.x;
  const int lane = t & 63;
  const int l15 = lane & 15, l4 = lane >> 4;
  const int wid = t >> 6;
  const int wr = wid >> 1, wc = wid & 1;

  const int L = blockIdx.x;
  const int chunk = (NBN * 1024) >> 3;
  const int w = (L & 7) * chunk + (L >> 3);
  const int bm = w / NBN, bn = w % NBN;

  const int goff = (lane >> 2) * 256 + (((lane & 3) ^ ((lane >> 3) & 3)) << 3);
  const bfu* Ab = A + (((size_t)(bm * 128)) << 8) + goff;
  const bfu* Bb = B + (((size_t)(bn * 128)) << 8) + goff;

  f32x4 acc[4][4] = {};

  auto STAGE = [&](int buf, int kt) {
    char* dst = lds + (buf << 14);
    const bfu* ga = Ab + (kt << 5);
    const bfu* gb = Bb + (kt << 5);
    #pragma unroll
    for (int r = 0; r < 2; ++r) {
      int rowg = (wid << 5) + (r << 4);
      gload_lds16(ga + (size_t)rowg * 256, dst + (rowg << 6));
      gload_lds16(gb + (size_t)rowg * 256, dst + 8192 + (rowg << 6));
    }
  };

  STAGE(0, 0);
  __syncthreads();

  for (int kt = 0; kt < 8; ++kt) {
    if (kt < 7) STAGE((kt + 1) & 1, kt + 1);
    const char* bufp = lds + ((kt & 1) << 14);

    bf16x8 af[4], bfr[4];
    #pragma unroll
    for (int ms = 0; ms < 4; ++ms) {
      int row = (wr << 6) + (ms << 4) + l15;
      int u = (l4 ^ ((row >> 1) & 3)) << 4;
      af[ms] = *(const bf16x8*)(bufp + (row << 6) + u);
    }
    #pragma unroll
    for (int ns = 0; ns < 4; ++ns) {
      int row = (wc << 6) + (ns << 4) + l15;
      int u = (l4 ^ ((row >> 1) & 3)) << 4;
      bfr[ns] = *(const bf16x8*)(bufp + 8192 + (row << 6) + u);
    }
    #pragma unroll
    for (int ms = 0; ms < 4; ++ms)
      #pragma unroll
      for (int ns = 0; ns < 4; ++ns)
        acc[ms][ns] = __builtin_amdgcn_mfma_f32_16x16x32_bf16(af[ms], bfr[ns], acc[ms][ns], 0, 0, 0);
    if (kt < 7) __syncthreads();
  }

  #pragma unroll
  for (int ns = 0; ns < 4; ++ns) {
    int n = bn * 128 + (wc << 6) + (ns << 4) + l15;
    float bb = bias[n];
    #pragma unroll
    for (int ms = 0; ms < 4; ++ms) {
      int m = bm * 128 + (wr << 6) + (ms << 4) + (l4 << 2);
      #pragma unroll
      for (int r = 0; r < 4; ++r)
        out[((size_t)(m + r) << 8) + n] = acc[ms][ns][r] + bb;
    }
  }
}

extern "C" void kernel_launch(void* const* d_in, const int* in_sizes, int n_in,
                              void* d_out, int out_size, void* d_ws, size_t ws_size,
                              hipStream_t stream)
{
  const float* x     = (const float*)d_in[0];
  const float* w_qkv = (const float*)d_in[1];
  const float* b_qkv = (const float*)d_in[2];
  const float* w_out = (const float*)d_in[3];
  const float* b_out = (const float*)d_in[4];
  const float* pe    = (const float*)d_in[5];
  const int*   rel   = (const int*)d_in[6];
  float* out = (float*)d_out;

  char* ws = (char*)d_ws;
  bfu*   attn_ws = (bfu*)(ws);                 // [131072][256] bf16 = 64 MiB
  float* bias_ws = (float*)(ws + 67108864);    // 4096 f32
  bfu*   wqB     = (bfu*)(ws + 67125248);      // 196608 bf16 [768][256]
  bfu*   woB     = (bfu*)(ws + 67518464);      // 65536 bf16 [256][256]

  prep_kernel<<<768, 256, 0, stream>>>(w_qkv, w_out, pe, rel, wqB, woB, bias_ws);
  qkv_attn<<<2048, 256, 0, stream>>>(x, wqB, b_qkv, bias_ws, attn_ws);
  mfma_gemm<2><<<2048, 256, 0, stream>>>(attn_ws, woB, b_out, out);
}

// Round 18
// 219.765 us; speedup vs baseline: 2.0191x; 2.0191x over previous
//
#include <hip/hip_runtime.h>

// bf16 handled as raw ushort (bf16 = top 16 bits of fp32).
typedef unsigned short bfu;
typedef unsigned int u32;
typedef __attribute__((ext_vector_type(8))) short bf16x8;   // 8 bf16 = 4 VGPRs
typedef __attribute__((ext_vector_type(4))) float f32x4;

#define SCALE_F 0.17677669529663687f

__device__ __forceinline__ bfu f2b(float f) {
  unsigned int u = __float_as_uint(f);
  u += 0x7fffu + ((u >> 16) & 1u);   // round-to-nearest-even
  return (bfu)(u >> 16);
}
__device__ __forceinline__ unsigned pk2(float a, float b) {
  return ((unsigned)f2b(b) << 16) | (unsigned)f2b(a);
}
__device__ __forceinline__ void gload_lds16(const void* g, void* l) {
  __builtin_amdgcn_global_load_lds(
      (const __attribute__((address_space(1))) u32*)g,
      (__attribute__((address_space(3))) u32*)l, 16, 0, 0);
}

// Prep: cvt w_qkv [768][256] f32 -> bf16 (N x K), w_out [256][256] likewise,
// and gather the 64x64 relative-position bias table (f32).
__global__ void prep_kernel(const float* __restrict__ wq, const float* __restrict__ wo,
                            const float* __restrict__ pe, const int* __restrict__ rel,
                            bfu* __restrict__ wqB, bfu* __restrict__ woB,
                            float* __restrict__ bias)
{
  int t = blockIdx.x * 256 + threadIdx.x;
  if (t < 196608) wqB[t] = f2b(wq[t]);
  if (t < 65536)  woB[t] = f2b(wo[t]);
  if (t < 4096)   { int r0 = rel[2 * t], r1 = rel[2 * t + 1]; bias[t] = pe[r0 * 15 + r1]; }
}

// Fused qkv-projection + window attention (r12-verified structure, best-known:
// qkv_attn 188 us). One block per (bl, win), 512 thr = 8 waves; wave = head.
// The three mini-GEMMs are fused into one kt loop (24 acc chains). Added vs
// r12: s_setprio(1) around pure-MFMA clusters (T5) — waves run phase-
// independent here, the regime where setprio measured +4-7% (m191).
// LDS: xwin [64 tok][256 c] bf16 unit-swizzled (32 KB) + per-wave
// {qs[64][40], ks[64][40] (80 B stride), vs[32][72] (144 B), inv[64] f32,
//  ps 8 KB aliasing qs+ks} = 15104 B. Total 153600 B.
__global__ __launch_bounds__(512, 2)
void qkv_attn(const float* __restrict__ x, const bfu* __restrict__ wqB,
              const float* __restrict__ b_qkv, const float* __restrict__ bias,
              bfu* __restrict__ aout)
{
  __shared__ __align__(16) char slds[153600];
  const int t = threadIdx.x;
  const int lane = t & 63, wid = t >> 6;       // wid = head = staging y-row
  const int l15 = lane & 15, l4 = lane >> 4;
  const int blwin = blockIdx.x;
  const int bl = blwin >> 8, win = blwin & 255;

  // Stage x window: wave w stages y-row w (8 tokens x 256 ch) as bf16.
  // phys: slds[tok*512 + (u ^ (tok&15))*16 + sub], u = channel-unit (8 ch).
  {
    int y = ((win >> 4) << 3) | wid;
    size_t rowbase = (((size_t)bl * 16384) + (size_t)y * 128 + ((win & 15) << 3)) * 256;
    const float* px = x + rowbase + (lane << 2);
    #pragma unroll
    for (int i = 0; i < 8; ++i) {
      float4 v = *(const float4*)(px + i * 256);
      uint2 d; d.x = pk2(v.x, v.y); d.y = pk2(v.z, v.w);
      int tok = (wid << 3) | i;
      *(uint2*)(slds + tok * 512 + (((lane >> 1) ^ (tok & 15)) << 4) + ((lane & 1) << 3)) = d;
    }
  }
  __syncthreads();

  char* wbl = slds + 32768 + wid * 15104;
  char* qsB = wbl;
  char* ksB = wbl + 5120;
  char* vsB = wbl + 10240;
  float* invB = (float*)(wbl + 14848);
  char* psB = wbl;   // aliases qs/ks AFTER qf/kf frags are in registers
  const int h = wid;

  // ---- fused Q/K/V mini-GEMMs (one kt loop, 24 acc chains) ----
  {
    const bfu* wQ = wqB + (size_t)(h * 32) * 256;
    const bfu* wK = wqB + (size_t)(256 + h * 32) * 256;
    const bfu* wV = wqB + (size_t)(512 + h * 32) * 256;
    const int woff = l15 * 256 + (l4 << 3);
    f32x4 aQ[2][4] = {}, aK[2][4] = {}, aV[4][2] = {};
    #pragma unroll
    for (int kt = 0; kt < 8; ++kt) {
      bf16x8 xf[4];
      #pragma unroll
      for (int m = 0; m < 4; ++m) {
        int tok = (m << 4) + l15;
        int u = ((kt << 2) + l4) ^ (tok & 15);
        xf[m] = *(const bf16x8*)(slds + tok * 512 + (u << 4));
      }
      bf16x8 q0 = *(const bf16x8*)(wQ + woff + (kt << 5));
      bf16x8 q1 = *(const bf16x8*)(wQ + woff + (kt << 5) + 4096);
      bf16x8 k0 = *(const bf16x8*)(wK + woff + (kt << 5));
      bf16x8 k1 = *(const bf16x8*)(wK + woff + (kt << 5) + 4096);
      bf16x8 v0 = *(const bf16x8*)(wV + woff + (kt << 5));
      bf16x8 v1 = *(const bf16x8*)(wV + woff + (kt << 5) + 4096);
      __builtin_amdgcn_s_setprio(1);
      #pragma unroll
      for (int m = 0; m < 4; ++m) {
        aQ[0][m] = __builtin_amdgcn_mfma_f32_16x16x32_bf16(q0, xf[m], aQ[0][m], 0, 0, 0);
        aQ[1][m] = __builtin_amdgcn_mfma_f32_16x16x32_bf16(q1, xf[m], aQ[1][m], 0, 0, 0);
        aK[0][m] = __builtin_amdgcn_mfma_f32_16x16x32_bf16(k0, xf[m], aK[0][m], 0, 0, 0);
        aK[1][m] = __builtin_amdgcn_mfma_f32_16x16x32_bf16(k1, xf[m], aK[1][m], 0, 0, 0);
        aV[m][0] = __builtin_amdgcn_mfma_f32_16x16x32_bf16(xf[m], v0, aV[m][0], 0, 0, 0);
        aV[m][1] = __builtin_amdgcn_mfma_f32_16x16x32_bf16(xf[m], v1, aV[m][1], 0, 0, 0);
      }
      __builtin_amdgcn_s_setprio(0);
    }

    // Q/K epilogue (swapped: D[c][tok], r spans c): qs/ks [tok][32c] stride 80 B.
    const float* bQ = b_qkv + h * 32;
    const float* bK = b_qkv + 256 + h * 32;
    #pragma unroll
    for (int n = 0; n < 2; ++n) {
      int c0 = (n << 4) + (l4 << 2);
      float4 bbq = *(const float4*)(bQ + c0);
      float4 bbk = *(const float4*)(bK + c0);
      #pragma unroll
      for (int m = 0; m < 4; ++m) {
        int tok = (m << 4) + l15;
        f32x4 a = aQ[n][m];
        ushort4 u4;
        u4.x = f2b(a[0] + bbq.x); u4.y = f2b(a[1] + bbq.y);
        u4.z = f2b(a[2] + bbq.z); u4.w = f2b(a[3] + bbq.w);
        *(ushort4*)(qsB + tok * 80 + (c0 << 1)) = u4;
        a = aK[n][m];
        u4.x = f2b(a[0] + bbk.x); u4.y = f2b(a[1] + bbk.y);
        u4.z = f2b(a[2] + bbk.z); u4.w = f2b(a[3] + bbk.w);
        *(ushort4*)(ksB + tok * 80 + (c0 << 1)) = u4;
      }
    }
    // V epilogue (normal: D[tok][c], r spans tok) -> vs [c][tok] stride 144 B.
    const float* bV = b_qkv + 512 + h * 32;
    #pragma unroll
    for (int m = 0; m < 4; ++m) {
      int tok0 = (m << 4) + (l4 << 2);
      #pragma unroll
      for (int n = 0; n < 2; ++n) {
        int c = (n << 4) + l15;
        float bbv = bV[c];
        f32x4 a = aV[m][n];
        ushort4 u4;
        u4.x = f2b(a[0] + bbv); u4.y = f2b(a[1] + bbv);
        u4.z = f2b(a[2] + bbv); u4.w = f2b(a[3] + bbv);
        *(ushort4*)(vsB + c * 144 + (tok0 << 1)) = u4;
      }
    }
  }

  // ---- attention (r12-verified per-wave structure) ----
  bf16x8 qf[4], kf[4];
  #pragma unroll
  for (int i = 0; i < 4; ++i) {
    qf[i] = *(const bf16x8*)(qsB + ((i << 4) + l15) * 80 + (l4 << 4));
    kf[i] = *(const bf16x8*)(ksB + ((i << 4) + l15) * 80 + (l4 << 4));
  }

  // S^T[j][i] = mfma(K, Q): reg r -> j = mj*16 + l4*4 + r; col i = ni*16 + l15.
  f32x4 st[4][4] = {};
  __builtin_amdgcn_s_setprio(1);
  #pragma unroll
  for (int mj = 0; mj < 4; ++mj)
    #pragma unroll
    for (int ni = 0; ni < 4; ++ni)
      st[mj][ni] = __builtin_amdgcn_mfma_f32_16x16x32_bf16(kf[mj], qf[ni], st[mj][ni], 0, 0, 0);
  __builtin_amdgcn_s_setprio(0);

  // scale + bias (bias table from global, L2-hot)
  #pragma unroll
  for (int ni = 0; ni < 4; ++ni) {
    int i = (ni << 4) + l15;
    #pragma unroll
    for (int mj = 0; mj < 4; ++mj) {
      float4 bb = *(const float4*)(bias + i * 64 + (mj << 4) + (l4 << 2));
      st[mj][ni][0] = fmaf(st[mj][ni][0], SCALE_F, bb.x);
      st[mj][ni][1] = fmaf(st[mj][ni][1], SCALE_F, bb.y);
      st[mj][ni][2] = fmaf(st[mj][ni][2], SCALE_F, bb.z);
      st[mj][ni][3] = fmaf(st[mj][ni][3], SCALE_F, bb.w);
    }
  }

  // qf/kf are in registers; ensure outstanding LDS reads retired before
  // overwriting their space with P (psB aliases qsB/ksB).
  asm volatile("s_waitcnt lgkmcnt(0)" ::: "memory");
  __builtin_amdgcn_sched_barrier(0);

  // softmax over j per owned q-row; unnormalized P -> swizzled psB.
  #pragma unroll
  for (int ni = 0; ni < 4; ++ni) {
    float mx = st[0][ni][0];
    #pragma unroll
    for (int mj = 0; mj < 4; ++mj)
      #pragma unroll
      for (int r = 0; r < 4; ++r)
        mx = fmaxf(mx, st[mj][ni][r]);
    mx = fmaxf(mx, __shfl_xor(mx, 16));
    mx = fmaxf(mx, __shfl_xor(mx, 32));
    float sum = 0.f;
    #pragma unroll
    for (int mj = 0; mj < 4; ++mj)
      #pragma unroll
      for (int r = 0; r < 4; ++r) {
        float p = __expf(st[mj][ni][r] - mx);
        st[mj][ni][r] = p;
        sum += p;
      }
    sum += __shfl_xor(sum, 16);
    sum += __shfl_xor(sum, 32);
    int i2 = (ni << 4) + l15;
    if (l4 == 0) invB[i2] = 1.0f / sum;
    const int swz = (i2 & 7) << 4;
    #pragma unroll
    for (int mj = 0; mj < 4; ++mj) {
      uint2 val;
      val.x = pk2(st[mj][ni][0], st[mj][ni][1]);
      val.y = pk2(st[mj][ni][2], st[mj][ni][3]);
      *(uint2*)(psB + i2 * 128 + (((mj << 5) + (l4 << 3)) ^ swz)) = val;
    }
  }

  // PV: O[i][c] = sum_j P[i][j] * Vt[c][j]
  bf16x8 vf[2][2];
  #pragma unroll
  for (int nj = 0; nj < 2; ++nj)
    #pragma unroll
    for (int ks = 0; ks < 2; ++ks)
      vf[nj][ks] = *(const bf16x8*)(vsB + ((nj << 4) + l15) * 144 + (ks << 6) + (l4 << 4));

  f32x4 oacc[4][2] = {};
  #pragma unroll
  for (int mi = 0; mi < 4; ++mi) {
    int i = (mi << 4) + l15;
    int swz = (i & 7) << 4;
    bf16x8 pf0 = *(const bf16x8*)(psB + i * 128 + ((l4 << 4) ^ swz));
    bf16x8 pf1 = *(const bf16x8*)(psB + i * 128 + ((64 + (l4 << 4)) ^ swz));
    __builtin_amdgcn_s_setprio(1);
    #pragma unroll
    for (int nj = 0; nj < 2; ++nj) {
      oacc[mi][nj] = __builtin_amdgcn_mfma_f32_16x16x32_bf16(pf0, vf[nj][0], oacc[mi][nj], 0, 0, 0);
      oacc[mi][nj] = __builtin_amdgcn_mfma_f32_16x16x32_bf16(pf1, vf[nj][1], oacc[mi][nj], 0, 0, 0);
    }
    __builtin_amdgcn_s_setprio(0);
  }

  // epilogue: row i = mi*16 + l4*4 + r, col c = nj*16 + l15
  #pragma unroll
  for (int mi = 0; mi < 4; ++mi) {
    #pragma unroll
    for (int r = 0; r < 4; ++r) {
      int tok = (mi << 4) + (l4 << 2) + r;
      float inv = invB[tok];
      int y = ((win >> 4) << 3) | (tok >> 3);
      int xp = ((win & 15) << 3) | (tok & 7);
      size_t p = ((size_t)bl * 128 + y) * 128 + xp;
      bfu* dst = aout + p * 256 + h * 32;
      #pragma unroll
      for (int nj = 0; nj < 2; ++nj)
        dst[(nj << 4) + l15] = f2b(oacc[mi][nj][r] * inv);
    }
  }
}

// Out-projection GEMM (round-8-verified): C[m][n] = sum_k A[m][k]*B[n][k] + bias[n].
// BK=32, double-buffered, STAGE(next) -> compute -> full barrier. f32 out.
template<int NBN>
__global__ __launch_bounds__(256)
void mfma_gemm(const bfu* __restrict__ A, const bfu* __restrict__ B,
               const float* __restrict__ bias, float* __restrict__ out)
{
  __shared__ __align__(16) char lds[32768];
  const int t = threadIdx.x;
  const int lane = t & 63;
  const int l15 = lane & 15, l4 = lane >> 4;
  const int wid = t >> 6;
  const int wr = wid >> 1, wc = wid & 1;

  const int L = blockIdx.x;
  const int chunk = (NBN * 1024) >> 3;
  const int w = (L & 7) * chunk + (L >> 3);
  const int bm = w / NBN, bn = w % NBN;

  const int goff = (lane >> 2) * 256 + (((lane & 3) ^ ((lane >> 3) & 3)) << 3);
  const bfu* Ab = A + (((size_t)(bm * 128)) << 8) + goff;
  const bfu* Bb = B + (((size_t)(bn * 128)) << 8) + goff;

  f32x4 acc[4][4] = {};

  auto STAGE = [&](int buf, int kt) {
    char* dst = lds + (buf << 14);
    const bfu* ga = Ab + (kt << 5);
    const bfu* gb = Bb + (kt << 5);
    #pragma unroll
    for (int r = 0; r < 2; ++r) {
      int rowg = (wid << 5) + (r << 4);
      gload_lds16(ga + (size_t)rowg * 256, dst + (rowg << 6));
      gload_lds16(gb + (size_t)rowg * 256, dst + 8192 + (rowg << 6));
    }
  };

  STAGE(0, 0);
  __syncthreads();

  for (int kt = 0; kt < 8; ++kt) {
    if (kt < 7) STAGE((kt + 1) & 1, kt + 1);
    const char* bufp = lds + ((kt & 1) << 14);

    bf16x8 af[4], bfr[4];
    #pragma unroll
    for (int ms = 0; ms < 4; ++ms) {
      int row = (wr << 6) + (ms << 4) + l15;
      int u = (l4 ^ ((row >> 1) & 3)) << 4;
      af[ms] = *(const bf16x8*)(bufp + (row << 6) + u);
    }
    #pragma unroll
    for (int ns = 0; ns < 4; ++ns) {
      int row = (wc << 6) + (ns << 4) + l15;
      int u = (l4 ^ ((row >> 1) & 3)) << 4;
      bfr[ns] = *(const bf16x8*)(bufp + 8192 + (row << 6) + u);
    }
    #pragma unroll
    for (int ms = 0; ms < 4; ++ms)
      #pragma unroll
      for (int ns = 0; ns < 4; ++ns)
        acc[ms][ns] = __builtin_amdgcn_mfma_f32_16x16x32_bf16(af[ms], bfr[ns], acc[ms][ns], 0, 0, 0);
    if (kt < 7) __syncthreads();
  }

  #pragma unroll
  for (int ns = 0; ns < 4; ++ns) {
    int n = bn * 128 + (wc << 6) + (ns << 4) + l15;
    float bb = bias[n];
    #pragma unroll
    for (int ms = 0; ms < 4; ++ms) {
      int m = bm * 128 + (wr << 6) + (ms << 4) + (l4 << 2);
      #pragma unroll
      for (int r = 0; r < 4; ++r)
        out[((size_t)(m + r) << 8) + n] = acc[ms][ns][r] + bb;
    }
  }
}

extern "C" void kernel_launch(void* const* d_in, const int* in_sizes, int n_in,
                              void* d_out, int out_size, void* d_ws, size_t ws_size,
                              hipStream_t stream)
{
  const float* x     = (const float*)d_in[0];
  const float* w_qkv = (const float*)d_in[1];
  const float* b_qkv = (const float*)d_in[2];
  const float* w_out = (const float*)d_in[3];
  const float* b_out = (const float*)d_in[4];
  const float* pe    = (const float*)d_in[5];
  const int*   rel   = (const int*)d_in[6];
  float* out = (float*)d_out;

  char* ws = (char*)d_ws;
  bfu*   attn_ws = (bfu*)(ws);                 // [131072][256] bf16 = 64 MiB
  float* bias_ws = (float*)(ws + 67108864);    // 4096 f32
  bfu*   wqB     = (bfu*)(ws + 67125248);      // 196608 bf16 [768][256]
  bfu*   woB     = (bfu*)(ws + 67518464);      // 65536 bf16 [256][256]

  prep_kernel<<<768, 256, 0, stream>>>(w_qkv, w_out, pe, rel, wqB, woB, bias_ws);
  qkv_attn<<<2048, 512, 0, stream>>>(x, wqB, b_qkv, bias_ws, attn_ws);
  mfma_gemm<2><<<2048, 256, 0, stream>>>(attn_ws, woB, b_out, out);
}

// Round 19
// 219.077 us; speedup vs baseline: 2.0254x; 1.0031x over previous
//
#include <hip/hip_runtime.h>

// bf16 handled as raw ushort (bf16 = top 16 bits of fp32).
typedef unsigned short bfu;
typedef unsigned int u32;
typedef __attribute__((ext_vector_type(8))) short bf16x8;   // 8 bf16 = 4 VGPRs
typedef __attribute__((ext_vector_type(4))) float f32x4;

#define SCALE_F 0.17677669529663687f

__device__ __forceinline__ bfu f2b(float f) {
  unsigned int u = __float_as_uint(f);
  u += 0x7fffu + ((u >> 16) & 1u);   // round-to-nearest-even
  return (bfu)(u >> 16);
}
__device__ __forceinline__ unsigned pk2(float a, float b) {
  return ((unsigned)f2b(b) << 16) | (unsigned)f2b(a);
}
__device__ __forceinline__ void gload_lds16(const void* g, void* l) {
  __builtin_amdgcn_global_load_lds(
      (const __attribute__((address_space(1))) u32*)g,
      (__attribute__((address_space(3))) u32*)l, 16, 0, 0);
}

// Prep: cvt w_qkv [768][256] f32 -> bf16 (N x K), w_out [256][256] likewise,
// and gather the 64x64 relative-position bias table (f32).
__global__ void prep_kernel(const float* __restrict__ wq, const float* __restrict__ wo,
                            const float* __restrict__ pe, const int* __restrict__ rel,
                            bfu* __restrict__ wqB, bfu* __restrict__ woB,
                            float* __restrict__ bias)
{
  int t = blockIdx.x * 256 + threadIdx.x;
  if (t < 196608) wqB[t] = f2b(wq[t]);
  if (t < 65536)  woB[t] = f2b(wo[t]);
  if (t < 4096)   { int r0 = rel[2 * t], r1 = rel[2 * t + 1]; bias[t] = pe[r0 * 15 + r1]; }
}

// Fused qkv-projection + window attention (r12-verified structure, champion:
// qkv_attn 188 us). One block per (bl, win), 512 thr = 8 waves; wave = head.
// Change vs r12: the kt loop's 6 weight fragments are explicitly DOUBLE-
// BUFFERED (kt=0 issued before the stage barrier; kt+1 issued before kt's
// MFMA burst). r12 loaded weights inside each iteration with immediate use ->
// one serialized L2 round-trip (~200-400 cy) per kt, and both waves/SIMD
// stall in lockstep. Pipelining converts 8 exposed latencies into 1.
// LDS: xwin [64 tok][256 c] bf16 unit-swizzled (32 KB) + per-wave
// {qs[64][40], ks[64][40] (80 B stride), vs[32][72] (144 B), inv[64] f32,
//  ps 8 KB aliasing qs+ks} = 15104 B. Total 153600 B.
__global__ __launch_bounds__(512, 2)
void qkv_attn(const float* __restrict__ x, const bfu* __restrict__ wqB,
              const float* __restrict__ b_qkv, const float* __restrict__ bias,
              bfu* __restrict__ aout)
{
  __shared__ __align__(16) char slds[153600];
  const int t = threadIdx.x;
  const int lane = t & 63, wid = t >> 6;       // wid = head = staging y-row
  const int l15 = lane & 15, l4 = lane >> 4;
  const int blwin = blockIdx.x;
  const int bl = blwin >> 8, win = blwin & 255;

  const int h = wid;
  const bfu* wQ = wqB + (size_t)(h * 32) * 256;
  const bfu* wK = wqB + (size_t)(256 + h * 32) * 256;
  const bfu* wV = wqB + (size_t)(512 + h * 32) * 256;
  const int woff = l15 * 256 + (l4 << 3);

  // Prefetch kt=0 weight fragments (no LDS dependence) — in flight during
  // the stage + barrier below; the barrier's vmcnt drain means they landed.
  bf16x8 cw0 = *(const bf16x8*)(wQ + woff);
  bf16x8 cw1 = *(const bf16x8*)(wQ + woff + 4096);
  bf16x8 cw2 = *(const bf16x8*)(wK + woff);
  bf16x8 cw3 = *(const bf16x8*)(wK + woff + 4096);
  bf16x8 cw4 = *(const bf16x8*)(wV + woff);
  bf16x8 cw5 = *(const bf16x8*)(wV + woff + 4096);

  // Stage x window: wave w stages y-row w (8 tokens x 256 ch) as bf16.
  // phys: slds[tok*512 + (u ^ (tok&15))*16 + sub], u = channel-unit (8 ch).
  {
    int y = ((win >> 4) << 3) | wid;
    size_t rowbase = (((size_t)bl * 16384) + (size_t)y * 128 + ((win & 15) << 3)) * 256;
    const float* px = x + rowbase + (lane << 2);
    #pragma unroll
    for (int i = 0; i < 8; ++i) {
      float4 v = *(const float4*)(px + i * 256);
      uint2 d; d.x = pk2(v.x, v.y); d.y = pk2(v.z, v.w);
      int tok = (wid << 3) | i;
      *(uint2*)(slds + tok * 512 + (((lane >> 1) ^ (tok & 15)) << 4) + ((lane & 1) << 3)) = d;
    }
  }
  __syncthreads();

  char* wbl = slds + 32768 + wid * 15104;
  char* qsB = wbl;
  char* ksB = wbl + 5120;
  char* vsB = wbl + 10240;
  float* invB = (float*)(wbl + 14848);
  char* psB = wbl;   // aliases qs/ks AFTER qf/kf frags are in registers

  // ---- fused Q/K/V mini-GEMMs (one kt loop, 24 acc chains, weights piped) ----
  {
    f32x4 aQ[2][4] = {}, aK[2][4] = {}, aV[4][2] = {};
    #pragma unroll
    for (int kt = 0; kt < 8; ++kt) {
      // Issue next iteration's weight loads first — they overlap this
      // iteration's LDS reads + MFMA burst.
      bf16x8 nw0, nw1, nw2, nw3, nw4, nw5;
      if (kt < 7) {
        const int o = (kt + 1) << 5;
        nw0 = *(const bf16x8*)(wQ + woff + o);
        nw1 = *(const bf16x8*)(wQ + woff + o + 4096);
        nw2 = *(const bf16x8*)(wK + woff + o);
        nw3 = *(const bf16x8*)(wK + woff + o + 4096);
        nw4 = *(const bf16x8*)(wV + woff + o);
        nw5 = *(const bf16x8*)(wV + woff + o + 4096);
      }
      bf16x8 xf[4];
      #pragma unroll
      for (int m = 0; m < 4; ++m) {
        int tok = (m << 4) + l15;
        int u = ((kt << 2) + l4) ^ (tok & 15);
        xf[m] = *(const bf16x8*)(slds + tok * 512 + (u << 4));
      }
      #pragma unroll
      for (int m = 0; m < 4; ++m) {
        aQ[0][m] = __builtin_amdgcn_mfma_f32_16x16x32_bf16(cw0, xf[m], aQ[0][m], 0, 0, 0);
        aQ[1][m] = __builtin_amdgcn_mfma_f32_16x16x32_bf16(cw1, xf[m], aQ[1][m], 0, 0, 0);
        aK[0][m] = __builtin_amdgcn_mfma_f32_16x16x32_bf16(cw2, xf[m], aK[0][m], 0, 0, 0);
        aK[1][m] = __builtin_amdgcn_mfma_f32_16x16x32_bf16(cw3, xf[m], aK[1][m], 0, 0, 0);
        aV[m][0] = __builtin_amdgcn_mfma_f32_16x16x32_bf16(xf[m], cw4, aV[m][0], 0, 0, 0);
        aV[m][1] = __builtin_amdgcn_mfma_f32_16x16x32_bf16(xf[m], cw5, aV[m][1], 0, 0, 0);
      }
      if (kt < 7) {
        cw0 = nw0; cw1 = nw1; cw2 = nw2; cw3 = nw3; cw4 = nw4; cw5 = nw5;
      }
    }

    // Q/K epilogue (swapped: D[c][tok], r spans c): qs/ks [tok][32c] stride 80 B.
    const float* bQ = b_qkv + h * 32;
    const float* bK = b_qkv + 256 + h * 32;
    #pragma unroll
    for (int n = 0; n < 2; ++n) {
      int c0 = (n << 4) + (l4 << 2);
      float4 bbq = *(const float4*)(bQ + c0);
      float4 bbk = *(const float4*)(bK + c0);
      #pragma unroll
      for (int m = 0; m < 4; ++m) {
        int tok = (m << 4) + l15;
        f32x4 a = aQ[n][m];
        ushort4 u4;
        u4.x = f2b(a[0] + bbq.x); u4.y = f2b(a[1] + bbq.y);
        u4.z = f2b(a[2] + bbq.z); u4.w = f2b(a[3] + bbq.w);
        *(ushort4*)(qsB + tok * 80 + (c0 << 1)) = u4;
        a = aK[n][m];
        u4.x = f2b(a[0] + bbk.x); u4.y = f2b(a[1] + bbk.y);
        u4.z = f2b(a[2] + bbk.z); u4.w = f2b(a[3] + bbk.w);
        *(ushort4*)(ksB + tok * 80 + (c0 << 1)) = u4;
      }
    }
    // V epilogue (normal: D[tok][c], r spans tok) -> vs [c][tok] stride 144 B.
    const float* bV = b_qkv + 512 + h * 32;
    #pragma unroll
    for (int m = 0; m < 4; ++m) {
      int tok0 = (m << 4) + (l4 << 2);
      #pragma unroll
      for (int n = 0; n < 2; ++n) {
        int c = (n << 4) + l15;
        float bbv = bV[c];
        f32x4 a = aV[m][n];
        ushort4 u4;
        u4.x = f2b(a[0] + bbv); u4.y = f2b(a[1] + bbv);
        u4.z = f2b(a[2] + bbv); u4.w = f2b(a[3] + bbv);
        *(ushort4*)(vsB + c * 144 + (tok0 << 1)) = u4;
      }
    }
  }

  // ---- attention (r12-verified per-wave structure) ----
  bf16x8 qf[4], kf[4];
  #pragma unroll
  for (int i = 0; i < 4; ++i) {
    qf[i] = *(const bf16x8*)(qsB + ((i << 4) + l15) * 80 + (l4 << 4));
    kf[i] = *(const bf16x8*)(ksB + ((i << 4) + l15) * 80 + (l4 << 4));
  }

  // S^T[j][i] = mfma(K, Q): reg r -> j = mj*16 + l4*4 + r; col i = ni*16 + l15.
  f32x4 st[4][4] = {};
  #pragma unroll
  for (int mj = 0; mj < 4; ++mj)
    #pragma unroll
    for (int ni = 0; ni < 4; ++ni)
      st[mj][ni] = __builtin_amdgcn_mfma_f32_16x16x32_bf16(kf[mj], qf[ni], st[mj][ni], 0, 0, 0);

  // scale + bias (bias table from global, L2-hot)
  #pragma unroll
  for (int ni = 0; ni < 4; ++ni) {
    int i = (ni << 4) + l15;
    #pragma unroll
    for (int mj = 0; mj < 4; ++mj) {
      float4 bb = *(const float4*)(bias + i * 64 + (mj << 4) + (l4 << 2));
      st[mj][ni][0] = fmaf(st[mj][ni][0], SCALE_F, bb.x);
      st[mj][ni][1] = fmaf(st[mj][ni][1], SCALE_F, bb.y);
      st[mj][ni][2] = fmaf(st[mj][ni][2], SCALE_F, bb.z);
      st[mj][ni][3] = fmaf(st[mj][ni][3], SCALE_F, bb.w);
    }
  }

  // qf/kf are in registers; ensure outstanding LDS reads retired before
  // overwriting their space with P (psB aliases qsB/ksB).
  asm volatile("s_waitcnt lgkmcnt(0)" ::: "memory");
  __builtin_amdgcn_sched_barrier(0);

  // softmax over j per owned q-row; unnormalized P -> swizzled psB.
  #pragma unroll
  for (int ni = 0; ni < 4; ++ni) {
    float mx = st[0][ni][0];
    #pragma unroll
    for (int mj = 0; mj < 4; ++mj)
      #pragma unroll
      for (int r = 0; r < 4; ++r)
        mx = fmaxf(mx, st[mj][ni][r]);
    mx = fmaxf(mx, __shfl_xor(mx, 16));
    mx = fmaxf(mx, __shfl_xor(mx, 32));
    float sum = 0.f;
    #pragma unroll
    for (int mj = 0; mj < 4; ++mj)
      #pragma unroll
      for (int r = 0; r < 4; ++r) {
        float p = __expf(st[mj][ni][r] - mx);
        st[mj][ni][r] = p;
        sum += p;
      }
    sum += __shfl_xor(sum, 16);
    sum += __shfl_xor(sum, 32);
    int i2 = (ni << 4) + l15;
    if (l4 == 0) invB[i2] = 1.0f / sum;
    const int swz = (i2 & 7) << 4;
    #pragma unroll
    for (int mj = 0; mj < 4; ++mj) {
      uint2 val;
      val.x = pk2(st[mj][ni][0], st[mj][ni][1]);
      val.y = pk2(st[mj][ni][2], st[mj][ni][3]);
      *(uint2*)(psB + i2 * 128 + (((mj << 5) + (l4 << 3)) ^ swz)) = val;
    }
  }

  // PV: O[i][c] = sum_j P[i][j] * Vt[c][j]
  bf16x8 vf[2][2];
  #pragma unroll
  for (int nj = 0; nj < 2; ++nj)
    #pragma unroll
    for (int ks = 0; ks < 2; ++ks)
      vf[nj][ks] = *(const bf16x8*)(vsB + ((nj << 4) + l15) * 144 + (ks << 6) + (l4 << 4));

  f32x4 oacc[4][2] = {};
  #pragma unroll
  for (int mi = 0; mi < 4; ++mi) {
    int i = (mi << 4) + l15;
    int swz = (i & 7) << 4;
    bf16x8 pf0 = *(const bf16x8*)(psB + i * 128 + ((l4 << 4) ^ swz));
    bf16x8 pf1 = *(const bf16x8*)(psB + i * 128 + ((64 + (l4 << 4)) ^ swz));
    #pragma unroll
    for (int nj = 0; nj < 2; ++nj) {
      oacc[mi][nj] = __builtin_amdgcn_mfma_f32_16x16x32_bf16(pf0, vf[nj][0], oacc[mi][nj], 0, 0, 0);
      oacc[mi][nj] = __builtin_amdgcn_mfma_f32_16x16x32_bf16(pf1, vf[nj][1], oacc[mi][nj], 0, 0, 0);
    }
  }

  // epilogue: row i = mi*16 + l4*4 + r, col c = nj*16 + l15
  #pragma unroll
  for (int mi = 0; mi < 4; ++mi) {
    #pragma unroll
    for (int r = 0; r < 4; ++r) {
      int tok = (mi << 4) + (l4 << 2) + r;
      float inv = invB[tok];
      int y = ((win >> 4) << 3) | (tok >> 3);
      int xp = ((win & 15) << 3) | (tok & 7);
      size_t p = ((size_t)bl * 128 + y) * 128 + xp;
      bfu* dst = aout + p * 256 + h * 32;
      #pragma unroll
      for (int nj = 0; nj < 2; ++nj)
        dst[(nj << 4) + l15] = f2b(oacc[mi][nj][r] * inv);
    }
  }
}

// Out-projection GEMM (round-8-verified): C[m][n] = sum_k A[m][k]*B[n][k] + bias[n].
// BK=32, double-buffered, STAGE(next) -> compute -> full barrier. f32 out.
template<int NBN>
__global__ __launch_bounds__(256)
void mfma_gemm(const bfu* __restrict__ A, const bfu* __restrict__ B,
               const float* __restrict__ bias, float* __restrict__ out)
{
  __shared__ __align__(16) char lds[32768];
  const int t = threadIdx.x;
  const int lane = t & 63;
  const int l15 = lane & 15, l4 = lane >> 4;
  const int wid = t >> 6;
  const int wr = wid >> 1, wc = wid & 1;

  const int L = blockIdx.x;
  const int chunk = (NBN * 1024) >> 3;
  const int w = (L & 7) * chunk + (L >> 3);
  const int bm = w / NBN, bn = w % NBN;

  const int goff = (lane >> 2) * 256 + (((lane & 3) ^ ((lane >> 3) & 3)) << 3);
  const bfu* Ab = A + (((size_t)(bm * 128)) << 8) + goff;
  const bfu* Bb = B + (((size_t)(bn * 128)) << 8) + goff;

  f32x4 acc[4][4] = {};

  auto STAGE = [&](int buf, int kt) {
    char* dst = lds + (buf << 14);
    const bfu* ga = Ab + (kt << 5);
    const bfu* gb = Bb + (kt << 5);
    #pragma unroll
    for (int r = 0; r < 2; ++r) {
      int rowg = (wid << 5) + (r << 4);
      gload_lds16(ga + (size_t)rowg * 256, dst + (rowg << 6));
      gload_lds16(gb + (size_t)rowg * 256, dst + 8192 + (rowg << 6));
    }
  };

  STAGE(0, 0);
  __syncthreads();

  for (int kt = 0; kt < 8; ++kt) {
    if (kt < 7) STAGE((kt + 1) & 1, kt + 1);
    const char* bufp = lds + ((kt & 1) << 14);

    bf16x8 af[4], bfr[4];
    #pragma unroll
    for (int ms = 0; ms < 4; ++ms) {
      int row = (wr << 6) + (ms << 4) + l15;
      int u = (l4 ^ ((row >> 1) & 3)) << 4;
      af[ms] = *(const bf16x8*)(bufp + (row << 6) + u);
    }
    #pragma unroll
    for (int ns = 0; ns < 4; ++ns) {
      int row = (wc << 6) + (ns << 4) + l15;
      int u = (l4 ^ ((row >> 1) & 3)) << 4;
      bfr[ns] = *(const bf16x8*)(bufp + 8192 + (row << 6) + u);
    }
    #pragma unroll
    for (int ms = 0; ms < 4; ++ms)
      #pragma unroll
      for (int ns = 0; ns < 4; ++ns)
        acc[ms][ns] = __builtin_amdgcn_mfma_f32_16x16x32_bf16(af[ms], bfr[ns], acc[ms][ns], 0, 0, 0);
    if (kt < 7) __syncthreads();
  }

  #pragma unroll
  for (int ns = 0; ns < 4; ++ns) {
    int n = bn * 128 + (wc << 6) + (ns << 4) + l15;
    float bb = bias[n];
    #pragma unroll
    for (int ms = 0; ms < 4; ++ms) {
      int m = bm * 128 + (wr << 6) + (ms << 4) + (l4 << 2);
      #pragma unroll
      for (int r = 0; r < 4; ++r)
        out[((size_t)(m + r) << 8) + n] = acc[ms][ns][r] + bb;
    }
  }
}

extern "C" void kernel_launch(void* const* d_in, const int* in_sizes, int n_in,
                              void* d_out, int out_size, void* d_ws, size_t ws_size,
                              hipStream_t stream)
{
  const float* x     = (const float*)d_in[0];
  const float* w_qkv = (const float*)d_in[1];
  const float* b_qkv = (const float*)d_in[2];
  const float* w_out = (const float*)d_in[3];
  const float* b_out = (const float*)d_in[4];
  const float* pe    = (const float*)d_in[5];
  const int*   rel   = (const int*)d_in[6];
  float* out = (float*)d_out;

  char* ws = (char*)d_ws;
  bfu*   attn_ws = (bfu*)(ws);                 // [131072][256] bf16 = 64 MiB
  float* bias_ws = (float*)(ws + 67108864);    // 4096 f32
  bfu*   wqB     = (bfu*)(ws + 67125248);      // 196608 bf16 [768][256]
  bfu*   woB     = (bfu*)(ws + 67518464);      // 65536 bf16 [256][256]

  prep_kernel<<<768, 256, 0, stream>>>(w_qkv, w_out, pe, rel, wqB, woB, bias_ws);
  qkv_attn<<<2048, 512, 0, stream>>>(x, wqB, b_qkv, bias_ws, attn_ws);
  mfma_gemm<2><<<2048, 256, 0, stream>>>(attn_ws, woB, b_out, out);
}